// Round 11
// baseline (193.785 us; speedup 1.0000x reference)
//
#include <hip/hip_runtime.h>
#include <math.h>

// R11: GEMM staging restructure — double-buffered LDS, ONE barrier per
// K-iter (was 2). Old: [barrier] stage(kt) [barrier = vmcnt(0) drain,
// nothing to overlap] compute(kt) -> full staging latency exposed each
// iter (qkv block: 2.5k MFMA cyc vs 44k total). New: [barrier] issue
// stage(kt+1) into buf^1, compute(kt) from buf -> the drain at the next
// barrier lands after compute, hiding the latency. LDS 64KB, 2 blocks/CU.
// Flash kernel unchanged from R10. Layouts verified R2-R10 (absmax 7.8e-3):
//   x32 A-frag: m=lane&15, k=(lane>>4)*8+j ; B-frag: n=lane&15, k=(lane>>4)*8+j
//   x16 A/B-frag: idx=lane&15, k=(lane>>4)*4+j
//   C/D (all 16x16): col=lane&15, row=(lane>>4)*4+reg

#define SS_ 2048
#define DD_ 1024
#define NH_ 16
#define BN_ 32
#define BS_ 4096

typedef __bf16 bf16x8 __attribute__((ext_vector_type(8)));
typedef __bf16 bf16x4 __attribute__((ext_vector_type(4)));
typedef short shortx4 __attribute__((ext_vector_type(4)));
typedef float floatx4 __attribute__((ext_vector_type(4)));
typedef unsigned short ushortx4 __attribute__((ext_vector_type(4)));

__device__ __forceinline__ unsigned short f2bf(float f) {
    union { float f; unsigned u; } v; v.f = f;
    unsigned r = v.u + 0x7FFFu + ((v.u >> 16) & 1u);   // RNE
    return (unsigned short)(r >> 16);
}

__device__ __forceinline__ floatx4 mfma_pv(bf16x4 a, bf16x4 b, floatx4 c) {
#if __has_builtin(__builtin_amdgcn_mfma_f32_16x16x16_bf16)
    return __builtin_amdgcn_mfma_f32_16x16x16_bf16(a, b, c, 0, 0, 0);
#else
    return __builtin_amdgcn_mfma_f32_16x16x16bf16_1k(
        __builtin_bit_cast(shortx4, a), __builtin_bit_cast(shortx4, b), c, 0, 0, 0);
#endif
}

__device__ __forceinline__ void gl_lds16(const unsigned short* g, unsigned short* l) {
    __builtin_amdgcn_global_load_lds(
        (const __attribute__((address_space(1))) unsigned int*)g,
        (__attribute__((address_space(3))) unsigned int*)l, 16, 0, 0);
}

// ---------- K0a: cast resid + WQ/WK/WV to bf16 ----------
__global__ __launch_bounds__(256) void cast_bf16_kernel(
    const float* __restrict__ resid, const float* __restrict__ WQ,
    const float* __restrict__ WK, const float* __restrict__ WV,
    unsigned short* __restrict__ residB, unsigned short* __restrict__ WQb,
    unsigned short* __restrict__ WKb, unsigned short* __restrict__ WVb)
{
    const int z = blockIdx.y;
    if (z > 0 && blockIdx.x >= 1024) return;
    const float* src = (z == 0) ? resid : (z == 1) ? WQ : (z == 2) ? WK : WV;
    unsigned short* dst = (z == 0) ? residB : (z == 1) ? WQb : (z == 2) ? WKb : WVb;
    const int i = (blockIdx.x * 256 + threadIdx.x) * 4;
    float4 f = *(const float4*)(src + i);
    ushortx4 o;
    o[0] = f2bf(f.x); o[1] = f2bf(f.y); o[2] = f2bf(f.z); o[3] = f2bf(f.w);
    *(ushortx4*)(dst + i) = o;
}

// ---------- K0b: WO [kk=n*64+h][d] fp32 -> WOt [d][kk] bf16 ----------
__global__ __launch_bounds__(256) void wo_transpose_kernel(
    const float* __restrict__ WO, unsigned short* __restrict__ WOt)
{
    __shared__ float t[64][65];
    const int kk0 = blockIdx.x * 64, d0 = blockIdx.y * 64;
    #pragma unroll
    for (int it = 0; it < 16; ++it) {
        int idx = it * 256 + threadIdx.x;
        int r = idx >> 6, c = idx & 63;
        t[r][c] = WO[(kk0 + r) * DD_ + d0 + c];
    }
    __syncthreads();
    #pragma unroll
    for (int it = 0; it < 16; ++it) {
        int idx = it * 256 + threadIdx.x;
        int r = idx >> 6, c = idx & 63;
        WOt[(d0 + r) * DD_ + kk0 + c] = f2bf(t[c][r]);
    }
}

// ---------- K1: QKV projections, dbuf m97 GEMM, swizzled LDS ----------
__global__ __launch_bounds__(256) void qkv_m97_kernel(
    const unsigned short* __restrict__ residB,
    const unsigned short* __restrict__ WQb,
    const unsigned short* __restrict__ WKb,
    const unsigned short* __restrict__ WVb,
    unsigned short* __restrict__ q, unsigned short* __restrict__ kk,
    unsigned short* __restrict__ vT)
{
    __shared__ unsigned short As[2][128 * 64];
    __shared__ unsigned short Bs[2][128 * 64];
    const int tid = threadIdx.x;
    const int l = tid & 63, w = tid >> 6;
    const int quad = l >> 4, lan = l & 15;
    const int z = blockIdx.z;
    const unsigned short* W = (z == 0) ? WQb : (z == 1) ? WKb : WVb;
    unsigned short* dst = (z == 0) ? q : (z == 1) ? kk : vT;
    const int mBase = blockIdx.x * 128;
    const int nBase = blockIdx.y * 128;
    const int wm = (w & 1) * 64, wn = (w >> 1) * 64;

    floatx4 acc[4][4];
    #pragma unroll
    for (int a = 0; a < 4; ++a)
        #pragma unroll
        for (int b = 0; b < 4; ++b)
            #pragma unroll
            for (int i = 0; i < 4; ++i) acc[a][b][i] = 0.f;

    const int sr = l >> 3;
    const int sgx = ((l & 7) ^ sr) * 8;

    #define QKV_STAGE(k0_, b_)                                                  \
        { _Pragma("unroll")                                                     \
          for (int i_ = 0; i_ < 4; ++i_) {                                      \
              const int row_ = i_ * 32 + w * 8 + sr;                            \
              gl_lds16(residB + (size_t)(mBase + row_) * DD_ + (k0_) + sgx,     \
                       As[b_] + i_ * 2048 + w * 512);                           \
              gl_lds16(W + (size_t)(nBase + row_) * DD_ + (k0_) + sgx,          \
                       Bs[b_] + i_ * 2048 + w * 512); } }

    QKV_STAGE(0, 0);
    for (int kt = 0; kt < 16; ++kt) {
        __syncthreads();                       // stage(kt) visible
        if (kt + 1 < 16) QKV_STAGE((kt + 1) * 64, (kt + 1) & 1);
        const int b = kt & 1;
        #pragma unroll
        for (int ks = 0; ks < 2; ++ks) {
            const int fo = (((ks * 4 + quad) ^ (lan & 7)) << 3);
            bf16x8 a[4], bb[4];
            #pragma unroll
            for (int mi = 0; mi < 4; ++mi)
                a[mi] = *(const bf16x8*)(As[b] + (wm + mi * 16 + lan) * 64 + fo);
            #pragma unroll
            for (int ni = 0; ni < 4; ++ni)
                bb[ni] = *(const bf16x8*)(Bs[b] + (wn + ni * 16 + lan) * 64 + fo);
            #pragma unroll
            for (int mi = 0; mi < 4; ++mi)
                #pragma unroll
                for (int ni = 0; ni < 4; ++ni)
                    acc[mi][ni] = __builtin_amdgcn_mfma_f32_16x16x32_bf16(
                        a[mi], bb[ni], acc[mi][ni], 0, 0, 0);
        }
    }
    #undef QKV_STAGE
    const int headU = (nBase + wn) >> 6;
    const float scale = (z == 0) ? 0.125f * 1.44269504088896340736f : 1.0f;
    if (z < 2) {
        #pragma unroll
        for (int mi = 0; mi < 4; ++mi)
            #pragma unroll
            for (int ni = 0; ni < 4; ++ni)
                #pragma unroll
                for (int reg = 0; reg < 4; ++reg) {
                    int m = mBase + wm + mi * 16 + quad * 4 + reg;
                    int bb = m >> 11, ss = m & 2047;
                    int h = ni * 16 + lan;
                    dst[((size_t)(bb * NH_ + headU) * SS_ + ss) * 64 + h] =
                        f2bf(acc[mi][ni][reg] * scale);
                }
    } else {
        #pragma unroll
        for (int mi = 0; mi < 4; ++mi) {
            const int m0 = mBase + wm + mi * 16 + quad * 4;
            const int bb = m0 >> 11, ss0 = m0 & 2047;
            #pragma unroll
            for (int ni = 0; ni < 4; ++ni) {
                const int h = ni * 16 + lan;
                bf16x4 ob;
                #pragma unroll
                for (int reg = 0; reg < 4; ++reg)
                    ob[reg] = static_cast<__bf16>(acc[mi][ni][reg]);
                *(bf16x4*)(dst + ((size_t)(bb * NH_ + headU) * 64 + h) * SS_ + ss0) = ob;
            }
        }
    }
}

// ---------- K2: flash attention, software-pipelined QK (R10) ----------
__global__ __launch_bounds__(256, 4) void flash_mfma_kernel(
    const unsigned short* __restrict__ q,
    const unsigned short* __restrict__ k,
    const unsigned short* __restrict__ vT,
    unsigned short* __restrict__ attn)
{
    __shared__ unsigned short ldsK[3][64 * 64];
    __shared__ unsigned short ldsV[2][64 * 64];
    const int l = threadIdx.x & 63, w = threadIdx.x >> 6;   // w: 0..3
    const int quad = l >> 4, lan = l & 15;
    const int f = blockIdx.x;                               // 0..1023
    const int bn = (f & 7) | (((f >> 3) & 3) << 3);         // XCD swizzle
    const int chunk = 31 - (f >> 5);                        // heavy blocks first

    const unsigned short* Qg = q  + (size_t)bn * SS_ * 64;
    const unsigned short* Kg = k  + (size_t)bn * SS_ * 64;
    const unsigned short* Vg = vT + (size_t)bn * 64 * SS_;

    const int srl = l >> 3;
    const int sgx = (l & 7) ^ srl;

    const int qRow0 = chunk * 64 + w * 16;
    const int qAbs = qRow0 + lan;

    const unsigned short* Qr = Qg + (size_t)qAbs * 64 + quad * 8;
    bf16x8 Qf0 = *(const bf16x8*)(Qr);
    bf16x8 Qf1 = *(const bf16x8*)(Qr + 32);

    bf16x4 ones;
    #pragma unroll
    for (int i = 0; i < 4; ++i) ones[i] = static_cast<__bf16>(1.0f);

    float mrow = -INFINITY;
    floatx4 l_acc;
    floatx4 o[4];
    #pragma unroll
    for (int i = 0; i < 4; ++i) l_acc[i] = 0.f;
    #pragma unroll
    for (int t = 0; t < 4; ++t)
        #pragma unroll
        for (int i = 0; i < 4; ++i) o[t][i] = 0.f;

    #define STAGE_K(kt_, buf_)                                                  \
        { const int row0_ = w * 16, kB_ = (kt_) * 64;                           \
          gl_lds16(Kg + (size_t)(kB_ + row0_ + srl) * 64 + sgx * 8,             \
                   &ldsK[buf_][row0_ * 64]);                                    \
          gl_lds16(Kg + (size_t)(kB_ + row0_ + 8 + srl) * 64 + sgx * 8,         \
                   &ldsK[buf_][(row0_ + 8) * 64]); }
    #define STAGE_V(kt_, buf_)                                                  \
        { const int row0_ = w * 16, kB_ = (kt_) * 64;                           \
          gl_lds16(Vg + (size_t)(row0_ + srl) * SS_ + kB_ + sgx * 8,            \
                   &ldsV[buf_][row0_ * 64]);                                    \
          gl_lds16(Vg + (size_t)(row0_ + 8 + srl) * SS_ + kB_ + sgx * 8,        \
                   &ldsV[buf_][(row0_ + 8) * 64]); }
    #define QK_TILE(dst_, buf_)                                                 \
        { const unsigned short* Kb_ = &ldsK[buf_][0];                           \
          _Pragma("unroll")                                                     \
          for (int nt = 0; nt < 4; ++nt) {                                      \
              const unsigned short* kr_ = Kb_ + (nt * 16 + lan) * 64;           \
              bf16x8 K0_ = *(const bf16x8*)(kr_ + ((quad ^ (lan & 7)) << 3));   \
              bf16x8 K1_ = *(const bf16x8*)(kr_ + (((quad + 4) ^ (lan & 7)) << 3)); \
              floatx4 zz_; zz_[0] = zz_[1] = zz_[2] = zz_[3] = 0.f;             \
              dst_[nt] = __builtin_amdgcn_mfma_f32_16x16x32_bf16(K0_, Qf0, zz_, 0, 0, 0); \
              dst_[nt] = __builtin_amdgcn_mfma_f32_16x16x32_bf16(K1_, Qf1, dst_[nt], 0, 0, 0); } }

    STAGE_K(0, 0);
    STAGE_V(0, 0);
    __syncthreads();
    if (chunk >= 1) STAGE_K(1, 1);
    floatx4 scCur[4], scNext[4];
    QK_TILE(scCur, 0);

    for (int kt = 0; kt <= chunk; ++kt) {
        const int kBase = kt * 64;
        __syncthreads();
        if (kt + 2 <= chunk) STAGE_K(kt + 2, (kt + 2) % 3);
        if (kt + 1 <= chunk) {
            STAGE_V(kt + 1, (kt + 1) & 1);
            QK_TILE(scNext, (kt + 1) % 3);
        }
        if (kt == chunk) {
            #pragma unroll
            for (int nt = 0; nt < 4; ++nt)
                #pragma unroll
                for (int reg = 0; reg < 4; ++reg)
                    if (kBase + nt * 16 + quad * 4 + reg > qAbs)
                        scCur[nt][reg] = -INFINITY;
        }
        float mx = scCur[0][0];
        #pragma unroll
        for (int nt = 0; nt < 4; ++nt)
            #pragma unroll
            for (int reg = 0; reg < 4; ++reg) mx = fmaxf(mx, scCur[nt][reg]);
        mx = fmaxf(mx, __shfl_xor(mx, 16, 64));
        mx = fmaxf(mx, __shfl_xor(mx, 32, 64));
        const float mnew = fmaxf(mrow, mx);
        if (!__all(mx <= mrow)) {
            const float alpha = exp2f(mrow - mnew);
            l_acc[0] *= alpha;
            #pragma unroll
            for (int t = 0; t < 4; ++t)
                #pragma unroll
                for (int i = 0; i < 4; ++i) o[t][i] *= alpha;
        }
        mrow = mnew;
        bf16x4 pb[4];
        #pragma unroll
        for (int nt = 0; nt < 4; ++nt)
            #pragma unroll
            for (int reg = 0; reg < 4; ++reg)
                pb[nt][reg] = static_cast<__bf16>(exp2f(scCur[nt][reg] - mnew));
        #pragma unroll
        for (int nt = 0; nt < 4; ++nt)
            l_acc = mfma_pv(ones, pb[nt], l_acc);
        const unsigned short* Vb = &ldsV[kt & 1][0];
        #pragma unroll
        for (int t = 0; t < 4; ++t) {
            const unsigned short* vr = Vb + (t * 16 + lan) * 64 + ((quad & 1) << 2);
            #pragma unroll
            for (int nt = 0; nt < 4; ++nt) {
                const int g = nt * 2 + (quad >> 1);
                bf16x4 Vf = *(const bf16x4*)(vr + ((g ^ (lan & 7)) << 3));
                o[t] = mfma_pv(Vf, pb[nt], o[t]);
            }
        }
        #pragma unroll
        for (int nt = 0; nt < 4; ++nt) scCur[nt] = scNext[nt];
    }
    const float rl = 1.f / l_acc[0];
    #pragma unroll
    for (int t = 0; t < 4; ++t) {
        bf16x4 ob;
        #pragma unroll
        for (int reg = 0; reg < 4; ++reg)
            ob[reg] = static_cast<__bf16>(o[t][reg] * rl);
        *(bf16x4*)(attn + ((size_t)bn * SS_ + qAbs) * 64 + t * 16 + quad * 4) = ob;
    }
    #undef STAGE_K
    #undef STAGE_V
    #undef QK_TILE
}

// ---------- K3: output projection, dbuf m97 GEMM, swizzled LDS ----------
__global__ __launch_bounds__(256) void out_m97_kernel(
    const unsigned short* __restrict__ attn,
    const unsigned short* __restrict__ WOt,
    float* __restrict__ out)
{
    __shared__ unsigned short As[2][128 * 64];
    __shared__ unsigned short Bs[2][128 * 64];
    const int tid = threadIdx.x;
    const int l = tid & 63, w = tid >> 6;
    const int quad = l >> 4, lan = l & 15;
    const int mBase = blockIdx.x * 128;
    const int nBase = blockIdx.y * 128;
    const int wm = (w & 1) * 64, wn = (w >> 1) * 64;
    const int bbU = mBase >> 11;
    const int ssBase = mBase & 2047;

    floatx4 acc[4][4];
    #pragma unroll
    for (int a = 0; a < 4; ++a)
        #pragma unroll
        for (int b = 0; b < 4; ++b)
            #pragma unroll
            for (int i = 0; i < 4; ++i) acc[a][b][i] = 0.f;

    const int sr = l >> 3;
    const int sgx = ((l & 7) ^ sr) * 8;

    #define OUT_STAGE(kt_, b_)                                                  \
        { _Pragma("unroll")                                                     \
          for (int i_ = 0; i_ < 4; ++i_) {                                      \
              const int row_ = i_ * 32 + w * 8 + sr;                            \
              gl_lds16(attn + ((size_t)(bbU * NH_ + (kt_)) * SS_ + ssBase + row_) * 64 + sgx, \
                       As[b_] + i_ * 2048 + w * 512);                           \
              gl_lds16(WOt + (size_t)(nBase + row_) * DD_ + (kt_) * 64 + sgx,   \
                       Bs[b_] + i_ * 2048 + w * 512); } }

    OUT_STAGE(0, 0);
    for (int kt = 0; kt < 16; ++kt) {
        __syncthreads();                       // stage(kt) visible
        if (kt + 1 < 16) OUT_STAGE(kt + 1, (kt + 1) & 1);
        const int b = kt & 1;
        #pragma unroll
        for (int ks = 0; ks < 2; ++ks) {
            const int fo = (((ks * 4 + quad) ^ (lan & 7)) << 3);
            bf16x8 a[4], bb[4];
            #pragma unroll
            for (int mi = 0; mi < 4; ++mi)
                a[mi] = *(const bf16x8*)(As[b] + (wm + mi * 16 + lan) * 64 + fo);
            #pragma unroll
            for (int ni = 0; ni < 4; ++ni)
                bb[ni] = *(const bf16x8*)(Bs[b] + (wn + ni * 16 + lan) * 64 + fo);
            #pragma unroll
            for (int mi = 0; mi < 4; ++mi)
                #pragma unroll
                for (int ni = 0; ni < 4; ++ni)
                    acc[mi][ni] = __builtin_amdgcn_mfma_f32_16x16x32_bf16(
                        a[mi], bb[ni], acc[mi][ni], 0, 0, 0);
        }
    }
    #undef OUT_STAGE
    #pragma unroll
    for (int mi = 0; mi < 4; ++mi)
        #pragma unroll
        for (int ni = 0; ni < 4; ++ni)
            #pragma unroll
            for (int reg = 0; reg < 4; ++reg) {
                int m = mBase + wm + mi * 16 + quad * 4 + reg;
                out[(size_t)m * DD_ + nBase + wn + ni * 16 + lan] = acc[mi][ni][reg];
            }
}

extern "C" void kernel_launch(void* const* d_in, const int* in_sizes, int n_in,
                              void* d_out, int out_size, void* d_ws, size_t ws_size,
                              hipStream_t stream) {
    const float* resid = (const float*)d_in[0];
    const float* WQ    = (const float*)d_in[1];
    const float* WK    = (const float*)d_in[2];
    const float* WV    = (const float*)d_in[3];
    const float* WO    = (const float*)d_in[4];
    float* out = (float*)d_out;

    unsigned short* q      = (unsigned short*)d_ws;
    unsigned short* kk     = q      + 4194304;
    unsigned short* vT     = kk     + 4194304;
    unsigned short* attn   = vT     + 4194304;
    unsigned short* residB = attn   + 4194304;
    unsigned short* WQb    = residB + 4194304;
    unsigned short* WKb    = WQb    + 1048576;
    unsigned short* WVb    = WKb    + 1048576;
    unsigned short* WOt    = WVb    + 1048576;

    cast_bf16_kernel<<<dim3(4096, 4), 256, 0, stream>>>(
        resid, WQ, WK, WV, residB, WQb, WKb, WVb);
    wo_transpose_kernel<<<dim3(16, 16), 256, 0, stream>>>(WO, WOt);
    qkv_m97_kernel<<<dim3(32, 8, 3), 256, 0, stream>>>(
        residB, WQb, WKb, WVb, q, kk, vT);
    flash_mfma_kernel<<<dim3(1024), dim3(256), 0, stream>>>(q, kk, vT, attn);
    out_m97_kernel<<<dim3(32, 8), 256, 0, stream>>>(attn, WOt, out);
}